// Round 2
// baseline (303.231 us; speedup 1.0000x reference)
//
#include <hip/hip_runtime.h>
#include <stdint.h>

typedef __attribute__((ext_vector_type(8))) short short8;   // 8 bf16 (4 VGPRs)
typedef __attribute__((ext_vector_type(4))) float f32x4;

#define LDS_AS __attribute__((address_space(3)))
#define GLOB_AS __attribute__((address_space(1)))

__device__ __forceinline__ void gload_lds16(const void* g, void* l) {
    __builtin_amdgcn_global_load_lds((const GLOB_AS uint32_t*)g,
                                     (LDS_AS uint32_t*)l, 16, 0, 0);
}

__device__ __forceinline__ unsigned short f2bf(float f) {
    uint32_t u = __builtin_bit_cast(uint32_t, f);
    u += 0x7fffu + ((u >> 16) & 1u);
    return (unsigned short)(u >> 16);
}
__device__ __forceinline__ float bf2f(unsigned short u) {
    uint32_t v = ((uint32_t)u) << 16;
    return __builtin_bit_cast(float, v);
}

// ---------------- fp32 -> bf16 convert ----------------
__global__ void cvt_kernel(const float* __restrict__ src,
                           unsigned short* __restrict__ dst, int n) {
    int i = (blockIdx.x * blockDim.x + threadIdx.x) * 4;
    if (i < n) {
        float4 v = *(const float4*)(src + i);
        ushort4 o;
        o.x = f2bf(v.x); o.y = f2bf(v.y); o.z = f2bf(v.z); o.w = f2bf(v.w);
        *(ushort4*)(dst + i) = o;
    }
}

// ---------------- rope tables: cos/sin (2048 x 32) ----------------
__global__ void rope_tables(float* __restrict__ cosT, float* __restrict__ sinT) {
    int tid = blockIdx.x * blockDim.x + threadIdx.x;  // 65536
    int t = tid >> 5, i = tid & 31;
    float f = (i < 16) ? exp2f(-10.0f * (float)i / 15.0f) : 0.0f;
    float th = (float)t * f;
    cosT[tid] = cosf(th);
    sinT[tid] = sinf(th);
}

// ---------------- GEMM C[m,n] = sum_k A[m,k]*B[n,k], bf16 in fp32 acc ----
// Double-buffered LDS, prefetch-before-compute, ONE barrier per K-step.
// MODE 1: qkv epilogue (split q/k/v per head; v lerped with v1 -> fp32 d_out)
// MODE 2: proj epilogue (fp32 + bias)
template <int MODE>
__global__ __launch_bounds__(256, 3) void gemm_bt(
    const unsigned short* __restrict__ A, const unsigned short* __restrict__ B,
    int K, int mtiles,
    unsigned short* __restrict__ qbuf, unsigned short* __restrict__ kbuf,
    float* __restrict__ vout, const float* __restrict__ v1,
    const float* __restrict__ lambp,
    float* __restrict__ y, const float* __restrict__ bias)
{
    __shared__ unsigned short As[2][128 * 32];
    __shared__ unsigned short Bs[2][128 * 32];
    const int tid = threadIdx.x;
    const int lane = tid & 63, w = tid >> 6;
    const int wr = w >> 1, wc = w & 1;
    const int lr = lane & 15, lh = lane >> 4;

    // bijective XCD chunk swizzle (gridDim.x % 8 == 0 for all our launches)
    const int nwg = gridDim.x;
    const int bid = blockIdx.x;
    const int sw = (bid & 7) * (nwg >> 3) + (bid >> 3);
    const long m0 = (long)(sw % mtiles) * 128;
    const long n0 = (long)(sw / mtiles) * 128;

    // staging addresses, computed once; bumped by 64 B per K-step
    const int row0 = w * 16 + (lane >> 2);
    const int colb = (lane & 3) * 16;
    const char* pa0 = (const char*)A + ((m0 + row0) * (long)K) * 2 + colb;
    const char* pa1 = pa0 + 64 * (long)K * 2;
    const char* pb0 = (const char*)B + ((n0 + row0) * (long)K) * 2 + colb;
    const char* pb1 = pb0 + 64 * (long)K * 2;
    char* la = (char*)&As[0][0] + w * 1024;   // wave-uniform LDS dests
    char* lb = (char*)&Bs[0][0] + w * 1024;
    const int BUF = 128 * 32 * 2;             // bytes per LDS buffer

    f32x4 acc[4][4] = {};

    auto STAGE = [&](int bo) {
        gload_lds16(pa0, la + bo);
        gload_lds16(pa1, la + bo + 4096);
        gload_lds16(pb0, lb + bo);
        gload_lds16(pb1, lb + bo + 4096);
        pa0 += 64; pa1 += 64; pb0 += 64; pb1 += 64;
    };
    auto COMPUTE = [&](int bo) {
        const unsigned short* as = (const unsigned short*)((const char*)&As[0][0] + bo);
        const unsigned short* bs = (const unsigned short*)((const char*)&Bs[0][0] + bo);
        short8 a[4], b[4];
        #pragma unroll
        for (int i = 0; i < 4; ++i)
            a[i] = *(const short8*)&as[(wr * 64 + i * 16 + lr) * 32 + lh * 8];
        #pragma unroll
        for (int i = 0; i < 4; ++i)
            b[i] = *(const short8*)&bs[(wc * 64 + i * 16 + lr) * 32 + lh * 8];
        #pragma unroll
        for (int i = 0; i < 4; ++i)
            #pragma unroll
            for (int j = 0; j < 4; ++j)
                acc[i][j] = __builtin_amdgcn_mfma_f32_16x16x32_bf16(
                    a[i], b[j], acc[i][j], 0, 0, 0);
    };

    STAGE(0);
    __syncthreads();                          // drains vmcnt(0) too
    for (int k0 = 0; k0 < K; k0 += 64) {      // K is a multiple of 64
        STAGE(BUF);                           // prefetch next tile into buf1
        COMPUTE(0);
        __syncthreads();
        if (k0 + 64 < K) STAGE(0);            // prefetch into buf0
        COMPUTE(BUF);
        __syncthreads();
    }

    float lam = 0.f;
    if constexpr (MODE == 1) lam = lambp[0];

    #pragma unroll
    for (int i = 0; i < 4; ++i)
    #pragma unroll
    for (int j = 0; j < 4; ++j)
    #pragma unroll
    for (int r = 0; r < 4; ++r) {
        long m = m0 + wr * 64 + i * 16 + lh * 4 + r;
        long n = n0 + wc * 64 + j * 16 + lr;
        float v = acc[i][j][r];
        if constexpr (MODE == 1) {
            int kk = (int)(n >> 10);
            int rem = (int)(n & 1023);
            int h = rem >> 6, d = rem & 63;
            long b_ = m >> 11, t = m & 2047;
            size_t idx = (((size_t)(b_ * 16 + h)) * 2048 + t) * 64 + d;
            if (kk == 0) qbuf[idx] = f2bf(v);
            else if (kk == 1) kbuf[idx] = f2bf(v);
            else {
                float vv = v1[(size_t)m * 1024 + rem];
                vout[idx] = (1.0f - lam) * v + lam * vv;
            }
        } else {
            y[(size_t)m * 1024 + n] = v + bias[n];
        }
    }
}

// ---------------- RMS-norm + rotary, in place on (B,H,T,64) bf16 ----------
__global__ __launch_bounds__(256) void normrope_kernel(
    unsigned short* __restrict__ qbuf, unsigned short* __restrict__ kbuf,
    const float* __restrict__ cosT, const float* __restrict__ sinT)
{
    int w = threadIdx.x >> 6, lane = threadIdx.x & 63;
    long rid = (long)blockIdx.x * 4 + w;          // 0 .. 262143
    unsigned short* buf = (rid < 131072) ? qbuf : kbuf;
    long r = rid & 131071;
    int t = (int)(r & 2047);
    float x = bf2f(buf[r * 64 + lane]);
    float ss = x * x;
    #pragma unroll
    for (int m = 1; m < 64; m <<= 1) ss += __shfl_xor(ss, m);
    float inv = rsqrtf(ss * (1.0f / 64.0f) + 1e-6f);
    float xn = x * inv;
    float partner = __shfl_xor(xn, 32);
    int d = lane & 31;
    float c = cosT[t * 32 + d], s = sinT[t * 32 + d];
    float yv = (lane < 32) ? (xn * c + partner * s) : (xn * c - partner * s);
    buf[r * 64 + lane] = f2bf(yv);
}

// ---------------- flash attention, sliding window ----------------
// block = 4 waves; block handles one (b,h) and 64 q rows; wave = 16 q rows.
__global__ __launch_bounds__(256, 2) void attn_kernel(
    const unsigned short* __restrict__ qn, const unsigned short* __restrict__ kn,
    const float* __restrict__ vout, unsigned short* __restrict__ attn_out,
    const int* __restrict__ winp)
{
    __shared__ unsigned short Vt[64][72];        // V^T tile: [d][key]
    __shared__ unsigned short Pl[4][16][72];     // per-wave P: [qrow][key]
    const int tid = threadIdx.x, lane = tid & 63, w = tid >> 6;
    const int lr = lane & 15, lh = lane >> 4;
    const int bh = blockIdx.x;                   // 0..63
    const int qt = blockIdx.y;                   // 0..31
    const int t0 = qt * 64;
    const int win = winp[0];
    const int qrow = t0 + w * 16;

    short8 qf[2];
    #pragma unroll
    for (int ks = 0; ks < 2; ++ks)
        qf[ks] = *(const short8*)&qn[((size_t)bh * 2048 + qrow + lr) * 64 + ks * 32 + lh * 8];

    f32x4 oacc[4] = {};
    float mrow[4], lrow[4];
    #pragma unroll
    for (int r = 0; r < 4; ++r) { mrow[r] = -1e30f; lrow[r] = 0.f; }

    int kvt0 = max(0, t0 - win + 1) >> 6;
    for (int kvt = kvt0; kvt <= qt; ++kvt) {
        int j0 = kvt * 64;
        __syncthreads();
        {   // stage V transposed (fp32 value -> bf16 LDS)
            int rr = tid >> 2, c0 = (tid & 3) * 16;
            const float* src = &vout[((size_t)bh * 2048 + j0 + rr) * 64 + c0];
            #pragma unroll
            for (int jj = 0; jj < 4; ++jj) {
                float4 f = *(const float4*)(src + jj * 4);
                Vt[c0 + jj * 4 + 0][rr] = f2bf(f.x);
                Vt[c0 + jj * 4 + 1][rr] = f2bf(f.y);
                Vt[c0 + jj * 4 + 2][rr] = f2bf(f.z);
                Vt[c0 + jj * 4 + 3][rr] = f2bf(f.w);
            }
        }
        __syncthreads();

        // S = Q K^T
        float sv[4][4];
        #pragma unroll
        for (int kt = 0; kt < 4; ++kt) {
            f32x4 s = {};
            #pragma unroll
            for (int ks = 0; ks < 2; ++ks) {
                short8 kf = *(const short8*)&kn[((size_t)bh * 2048 + j0 + kt * 16 + lr) * 64 + ks * 32 + lh * 8];
                s = __builtin_amdgcn_mfma_f32_16x16x32_bf16(qf[ks], kf, s, 0, 0, 0);
            }
            #pragma unroll
            for (int r = 0; r < 4; ++r) {
                int qi = qrow + lh * 4 + r;
                int ji = j0 + kt * 16 + lr;
                bool ok = (ji <= qi) && (qi - ji < win);
                sv[kt][r] = ok ? s[r] * 0.125f : -1e30f;
            }
        }

        // online softmax (rows live on lanes sharing lh; reduce across lr)
        float pn[4][4];
        #pragma unroll
        for (int r = 0; r < 4; ++r) {
            float tm = fmaxf(fmaxf(sv[0][r], sv[1][r]), fmaxf(sv[2][r], sv[3][r]));
            #pragma unroll
            for (int m = 1; m < 16; m <<= 1) tm = fmaxf(tm, __shfl_xor(tm, m));
            float nm = fmaxf(mrow[r], tm);
            float alpha = __expf(mrow[r] - nm);
            float ps = 0.f;
            #pragma unroll
            for (int kt = 0; kt < 4; ++kt) {
                float p = __expf(sv[kt][r] - nm);
                pn[kt][r] = p; ps += p;
            }
            #pragma unroll
            for (int m = 1; m < 16; m <<= 1) ps += __shfl_xor(ps, m);
            lrow[r] = lrow[r] * alpha + ps;
            mrow[r] = nm;
            #pragma unroll
            for (int dt = 0; dt < 4; ++dt) oacc[dt][r] *= alpha;
        }

        // P -> per-wave LDS (transpose to A-fragment layout)
        #pragma unroll
        for (int kt = 0; kt < 4; ++kt)
            #pragma unroll
            for (int r = 0; r < 4; ++r)
                Pl[w][lh * 4 + r][kt * 16 + lr] = f2bf(pn[kt][r]);

        short8 pf[2];
        #pragma unroll
        for (int ks = 0; ks < 2; ++ks)
            pf[ks] = *(const short8*)&Pl[w][lr][ks * 32 + lh * 8];
        #pragma unroll
        for (int dt = 0; dt < 4; ++dt)
            #pragma unroll
            for (int ks = 0; ks < 2; ++ks) {
                short8 vf = *(const short8*)&Vt[dt * 16 + lr][ks * 32 + lh * 8];
                oacc[dt] = __builtin_amdgcn_mfma_f32_16x16x32_bf16(pf[ks], vf, oacc[dt], 0, 0, 0);
            }
    }

    // write attention output (B,T,C) bf16
    int b = bh >> 4, h = bh & 15;
    #pragma unroll
    for (int dt = 0; dt < 4; ++dt)
        #pragma unroll
        for (int r = 0; r < 4; ++r) {
            int t = qrow + lh * 4 + r;
            float o = oacc[dt][r] / lrow[r];
            attn_out[((size_t)b * 2048 + t) * 1024 + h * 64 + dt * 16 + lr] = f2bf(o);
        }
}

extern "C" void kernel_launch(void* const* d_in, const int* in_sizes, int n_in,
                              void* d_out, int out_size, void* d_ws, size_t ws_size,
                              hipStream_t stream) {
    const float* x    = (const float*)d_in[0];
    const float* v1   = (const float*)d_in[1];
    const float* qkvw = (const float*)d_in[2];
    const float* cpw  = (const float*)d_in[3];
    const float* cpb  = (const float*)d_in[4];
    const float* lamb = (const float*)d_in[5];
    const int*   winp = (const int*)d_in[6];

    float* y    = (float*)d_out;
    float* vout = y + (size_t)8192 * 1024;   // value output (B,H,T,64) fp32

    char* ws = (char*)d_ws;
    unsigned short* xb   = (unsigned short*)(ws);                 // 16MB (reused as attn_out)
    unsigned short* Wb   = (unsigned short*)(ws + (16u << 20));   // 6MB
    unsigned short* Wp   = (unsigned short*)(ws + (22u << 20));   // 2MB
    unsigned short* qbuf = (unsigned short*)(ws + (24u << 20));   // 16MB
    unsigned short* kbuf = (unsigned short*)(ws + (40u << 20));   // 16MB
    float* cosT = (float*)(ws + (56u << 20));                     // 256KB
    float* sinT = (float*)(ws + (56u << 20) + (256u << 10));      // 256KB

    cvt_kernel<<<8388608 / 1024, 256, 0, stream>>>(x, xb, 8388608);
    cvt_kernel<<<3145728 / 1024, 256, 0, stream>>>(qkvw, Wb, 3145728);
    cvt_kernel<<<1048576 / 1024, 256, 0, stream>>>(cpw, Wp, 1048576);
    rope_tables<<<65536 / 256, 256, 0, stream>>>(cosT, sinT);

    gemm_bt<1><<<dim3(64 * 24), 256, 0, stream>>>(xb, Wb, 1024, 64,
        qbuf, kbuf, vout, v1, lamb, nullptr, nullptr);

    normrope_kernel<<<65536, 256, 0, stream>>>(qbuf, kbuf, cosT, sinT);

    attn_kernel<<<dim3(64, 32), 256, 0, stream>>>(qbuf, kbuf, vout, xb, winp);

    gemm_bt<2><<<dim3(64 * 8), 256, 0, stream>>>(xb, Wp, 1024, 64,
        nullptr, nullptr, nullptr, nullptr, nullptr, y, cpb);
}

// Round 3
// 215.792 us; speedup vs baseline: 1.4052x; 1.4052x over previous
//
#include <hip/hip_runtime.h>
#include <stdint.h>

typedef __attribute__((ext_vector_type(8))) short short8;   // 8 bf16 (4 VGPRs)
typedef __attribute__((ext_vector_type(4))) float f32x4;

#define LDS_AS __attribute__((address_space(3)))
#define GLOB_AS __attribute__((address_space(1)))

__device__ __forceinline__ void gload_lds16(const void* g, void* l) {
    __builtin_amdgcn_global_load_lds((const GLOB_AS uint32_t*)g,
                                     (LDS_AS uint32_t*)l, 16, 0, 0);
}

__device__ __forceinline__ unsigned short f2bf(float f) {
    uint32_t u = __builtin_bit_cast(uint32_t, f);
    u += 0x7fffu + ((u >> 16) & 1u);
    return (unsigned short)(u >> 16);
}
__device__ __forceinline__ float bf2f(unsigned short u) {
    uint32_t v = ((uint32_t)u) << 16;
    return __builtin_bit_cast(float, v);
}

// ---------------- fp32 -> bf16 convert ----------------
__global__ void cvt_kernel(const float* __restrict__ src,
                           unsigned short* __restrict__ dst, int n) {
    int i = (blockIdx.x * blockDim.x + threadIdx.x) * 4;
    if (i < n) {
        float4 v = *(const float4*)(src + i);
        ushort4 o;
        o.x = f2bf(v.x); o.y = f2bf(v.y); o.z = f2bf(v.z); o.w = f2bf(v.w);
        *(ushort4*)(dst + i) = o;
    }
}

// ---------------- rope tables: cos/sin (2048 x 32) ----------------
__global__ void rope_tables(float* __restrict__ cosT, float* __restrict__ sinT) {
    int tid = blockIdx.x * blockDim.x + threadIdx.x;  // 65536
    int t = tid >> 5, i = tid & 31;
    float f = (i < 16) ? exp2f(-10.0f * (float)i / 15.0f) : 0.0f;
    float th = (float)t * f;
    cosT[tid] = cosf(th);
    sinT[tid] = sinf(th);
}

// ---------------- GEMM C[m,n] = sum_k A[m,k]*B[n,k], bf16 in fp32 acc ----
// Double-buffered LDS, prefetch-before-compute, natural dim3 raster (good L2).
// MODE 1: qkv epilogue: q/k get fused RMS-norm + RoPE -> bf16 (B,H,T,64);
//         v gets lerped with v1 -> fp32 d_out.
// MODE 2: proj epilogue (fp32 + bias)
template <int MODE>
__global__ __launch_bounds__(256, 3) void gemm_bt(
    const unsigned short* __restrict__ A, const unsigned short* __restrict__ B,
    int K,
    unsigned short* __restrict__ qbuf, unsigned short* __restrict__ kbuf,
    float* __restrict__ vout, const float* __restrict__ v1,
    const float* __restrict__ lambp,
    float* __restrict__ y, const float* __restrict__ bias,
    const float* __restrict__ cosT, const float* __restrict__ sinT)
{
    __shared__ unsigned short As[2][128 * 32];
    __shared__ unsigned short Bs[2][128 * 32];
    const int tid = threadIdx.x;
    const int lane = tid & 63, w = tid >> 6;
    const int wr = w >> 1, wc = w & 1;
    const int lr = lane & 15, lh = lane >> 4;
    const long m0 = (long)blockIdx.x * 128;
    const long n0 = (long)blockIdx.y * 128;

    // staging addresses, computed once; bumped by 64 B per K-step
    const int row0 = w * 16 + (lane >> 2);
    const int colb = (lane & 3) * 16;
    const char* pa0 = (const char*)A + ((m0 + row0) * (long)K) * 2 + colb;
    const char* pa1 = pa0 + 64 * (long)K * 2;
    const char* pb0 = (const char*)B + ((n0 + row0) * (long)K) * 2 + colb;
    const char* pb1 = pb0 + 64 * (long)K * 2;
    char* la = (char*)&As[0][0] + w * 1024;   // wave-uniform LDS dests
    char* lb = (char*)&Bs[0][0] + w * 1024;
    const int BUF = 128 * 32 * 2;             // bytes per LDS buffer

    f32x4 acc[4][4] = {};

    auto STAGE = [&](int bo) {
        gload_lds16(pa0, la + bo);
        gload_lds16(pa1, la + bo + 4096);
        gload_lds16(pb0, lb + bo);
        gload_lds16(pb1, lb + bo + 4096);
        pa0 += 64; pa1 += 64; pb0 += 64; pb1 += 64;
    };
    auto COMPUTE = [&](int bo) {
        const unsigned short* as = (const unsigned short*)((const char*)&As[0][0] + bo);
        const unsigned short* bs = (const unsigned short*)((const char*)&Bs[0][0] + bo);
        short8 a[4], b[4];
        #pragma unroll
        for (int i = 0; i < 4; ++i)
            a[i] = *(const short8*)&as[(wr * 64 + i * 16 + lr) * 32 + lh * 8];
        #pragma unroll
        for (int i = 0; i < 4; ++i)
            b[i] = *(const short8*)&bs[(wc * 64 + i * 16 + lr) * 32 + lh * 8];
        #pragma unroll
        for (int i = 0; i < 4; ++i)
            #pragma unroll
            for (int j = 0; j < 4; ++j)
                acc[i][j] = __builtin_amdgcn_mfma_f32_16x16x32_bf16(
                    a[i], b[j], acc[i][j], 0, 0, 0);
    };

    STAGE(0);
    __syncthreads();                          // drains vmcnt(0) too
    for (int k0 = 0; k0 < K; k0 += 64) {      // K is a multiple of 64
        STAGE(BUF);                           // prefetch next tile into buf1
        COMPUTE(0);
        __syncthreads();
        if (k0 + 64 < K) STAGE(0);            // prefetch into buf0
        COMPUTE(BUF);
        __syncthreads();
    }

    if constexpr (MODE == 1) {
        const long nbase = n0 + wc * 64;      // wave-uniform, 64-aligned
        const int kk = (int)(nbase >> 10);    // 0=q 1=k 2=v (uniform)
        const int h = (int)((nbase & 1023) >> 6);
        if (kk == 2) {
            float lam = lambp[0];
            #pragma unroll
            for (int i = 0; i < 4; ++i)
            #pragma unroll
            for (int j = 0; j < 4; ++j)
            #pragma unroll
            for (int r = 0; r < 4; ++r) {
                long m = m0 + wr * 64 + i * 16 + lh * 4 + r;
                long n = nbase + j * 16 + lr;
                int rem = (int)(n & 1023);
                int d = rem & 63;
                long b_ = m >> 11, t = m & 2047;
                size_t idx = (((size_t)(b_ * 16 + (rem >> 6))) * 2048 + t) * 64 + d;
                float vv = v1[(size_t)m * 1024 + rem];
                vout[idx] = (1.0f - lam) * acc[i][j][r] + lam * vv;
            }
        } else {
            unsigned short* dst = (kk == 0) ? qbuf : kbuf;
            #pragma unroll
            for (int i = 0; i < 4; ++i)
            #pragma unroll
            for (int r = 0; r < 4; ++r) {
                float v0 = acc[i][0][r], v1_ = acc[i][1][r];
                float v2 = acc[i][2][r], v3 = acc[i][3][r];
                float ss = v0 * v0 + v1_ * v1_ + v2 * v2 + v3 * v3;
                ss += __shfl_xor(ss, 1);
                ss += __shfl_xor(ss, 2);
                ss += __shfl_xor(ss, 4);
                ss += __shfl_xor(ss, 8);
                float inv = rsqrtf(ss * (1.0f / 64.0f) + 1e-6f);
                float x0 = v0 * inv, x1 = v1_ * inv;
                float x2 = v2 * inv, x3 = v3 * inv;
                long m = m0 + wr * 64 + i * 16 + lh * 4 + r;
                int t = (int)(m & 2047);
                long b_ = m >> 11;
                float c0 = cosT[t * 32 + lr],      s0 = sinT[t * 32 + lr];
                float c1 = cosT[t * 32 + 16 + lr], s1 = sinT[t * 32 + 16 + lr];
                size_t rb = (((size_t)(b_ * 16 + h)) * 2048 + t) * 64;
                dst[rb + 0 * 16 + lr] = f2bf( x0 * c0 + x2 * s0);
                dst[rb + 1 * 16 + lr] = f2bf( x1 * c1 + x3 * s1);
                dst[rb + 2 * 16 + lr] = f2bf(-x0 * s0 + x2 * c0);
                dst[rb + 3 * 16 + lr] = f2bf(-x1 * s1 + x3 * c1);
            }
        }
    } else {
        #pragma unroll
        for (int i = 0; i < 4; ++i)
        #pragma unroll
        for (int j = 0; j < 4; ++j)
        #pragma unroll
        for (int r = 0; r < 4; ++r) {
            long m = m0 + wr * 64 + i * 16 + lh * 4 + r;
            long n = n0 + wc * 64 + j * 16 + lr;
            y[(size_t)m * 1024 + n] = acc[i][j][r] + bias[n];
        }
    }
}

// ---------------- flash attention, sliding window ----------------
// block = 4 waves; block handles one (b,h) and 64 q rows; wave = 16 q rows.
__global__ __launch_bounds__(256, 2) void attn_kernel(
    const unsigned short* __restrict__ qn, const unsigned short* __restrict__ kn,
    const float* __restrict__ vout, unsigned short* __restrict__ attn_out,
    const int* __restrict__ winp)
{
    __shared__ unsigned short Vt[64][72];        // V^T tile: [d][key]
    __shared__ unsigned short Pl[4][16][72];     // per-wave P: [qrow][key]
    const int tid = threadIdx.x, lane = tid & 63, w = tid >> 6;
    const int lr = lane & 15, lh = lane >> 4;
    const int bh = blockIdx.x;                   // 0..63
    const int qt = blockIdx.y;                   // 0..31
    const int t0 = qt * 64;
    const int win = winp[0];
    const int qrow = t0 + w * 16;

    short8 qf[2];
    #pragma unroll
    for (int ks = 0; ks < 2; ++ks)
        qf[ks] = *(const short8*)&qn[((size_t)bh * 2048 + qrow + lr) * 64 + ks * 32 + lh * 8];

    f32x4 oacc[4] = {};
    float mrow[4], lrow[4];
    #pragma unroll
    for (int r = 0; r < 4; ++r) { mrow[r] = -1e30f; lrow[r] = 0.f; }

    int kvt0 = max(0, t0 - win + 1) >> 6;
    for (int kvt = kvt0; kvt <= qt; ++kvt) {
        int j0 = kvt * 64;
        __syncthreads();
        {   // stage V transposed (fp32 value -> bf16 LDS)
            int rr = tid >> 2, c0 = (tid & 3) * 16;
            const float* src = &vout[((size_t)bh * 2048 + j0 + rr) * 64 + c0];
            #pragma unroll
            for (int jj = 0; jj < 4; ++jj) {
                float4 f = *(const float4*)(src + jj * 4);
                Vt[c0 + jj * 4 + 0][rr] = f2bf(f.x);
                Vt[c0 + jj * 4 + 1][rr] = f2bf(f.y);
                Vt[c0 + jj * 4 + 2][rr] = f2bf(f.z);
                Vt[c0 + jj * 4 + 3][rr] = f2bf(f.w);
            }
        }
        __syncthreads();

        // S = Q K^T
        float sv[4][4];
        #pragma unroll
        for (int kt = 0; kt < 4; ++kt) {
            f32x4 s = {};
            #pragma unroll
            for (int ks = 0; ks < 2; ++ks) {
                short8 kf = *(const short8*)&kn[((size_t)bh * 2048 + j0 + kt * 16 + lr) * 64 + ks * 32 + lh * 8];
                s = __builtin_amdgcn_mfma_f32_16x16x32_bf16(qf[ks], kf, s, 0, 0, 0);
            }
            #pragma unroll
            for (int r = 0; r < 4; ++r) {
                int qi = qrow + lh * 4 + r;
                int ji = j0 + kt * 16 + lr;
                bool ok = (ji <= qi) && (qi - ji < win);
                sv[kt][r] = ok ? s[r] * 0.125f : -1e30f;
            }
        }

        // online softmax (rows live on lanes sharing lh; reduce across lr)
        float pn[4][4];
        #pragma unroll
        for (int r = 0; r < 4; ++r) {
            float tm = fmaxf(fmaxf(sv[0][r], sv[1][r]), fmaxf(sv[2][r], sv[3][r]));
            #pragma unroll
            for (int m = 1; m < 16; m <<= 1) tm = fmaxf(tm, __shfl_xor(tm, m));
            float nm = fmaxf(mrow[r], tm);
            float alpha = __expf(mrow[r] - nm);
            float ps = 0.f;
            #pragma unroll
            for (int kt = 0; kt < 4; ++kt) {
                float p = __expf(sv[kt][r] - nm);
                pn[kt][r] = p; ps += p;
            }
            #pragma unroll
            for (int m = 1; m < 16; m <<= 1) ps += __shfl_xor(ps, m);
            lrow[r] = lrow[r] * alpha + ps;
            mrow[r] = nm;
            #pragma unroll
            for (int dt = 0; dt < 4; ++dt) oacc[dt][r] *= alpha;
        }

        // P -> per-wave LDS (transpose to A-fragment layout)
        #pragma unroll
        for (int kt = 0; kt < 4; ++kt)
            #pragma unroll
            for (int r = 0; r < 4; ++r)
                Pl[w][lh * 4 + r][kt * 16 + lr] = f2bf(pn[kt][r]);

        short8 pf[2];
        #pragma unroll
        for (int ks = 0; ks < 2; ++ks)
            pf[ks] = *(const short8*)&Pl[w][lr][ks * 32 + lh * 8];
        #pragma unroll
        for (int dt = 0; dt < 4; ++dt)
            #pragma unroll
            for (int ks = 0; ks < 2; ++ks) {
                short8 vf = *(const short8*)&Vt[dt * 16 + lr][ks * 32 + lh * 8];
                oacc[dt] = __builtin_amdgcn_mfma_f32_16x16x32_bf16(pf[ks], vf, oacc[dt], 0, 0, 0);
            }
    }

    // write attention output (B,T,C) bf16
    int b = bh >> 4, h = bh & 15;
    #pragma unroll
    for (int dt = 0; dt < 4; ++dt)
        #pragma unroll
        for (int r = 0; r < 4; ++r) {
            int t = qrow + lh * 4 + r;
            float o = oacc[dt][r] / lrow[r];
            attn_out[((size_t)b * 2048 + t) * 1024 + h * 64 + dt * 16 + lr] = f2bf(o);
        }
}

extern "C" void kernel_launch(void* const* d_in, const int* in_sizes, int n_in,
                              void* d_out, int out_size, void* d_ws, size_t ws_size,
                              hipStream_t stream) {
    const float* x    = (const float*)d_in[0];
    const float* v1   = (const float*)d_in[1];
    const float* qkvw = (const float*)d_in[2];
    const float* cpw  = (const float*)d_in[3];
    const float* cpb  = (const float*)d_in[4];
    const float* lamb = (const float*)d_in[5];
    const int*   winp = (const int*)d_in[6];

    float* y    = (float*)d_out;
    float* vout = y + (size_t)8192 * 1024;   // value output (B,H,T,64) fp32

    char* ws = (char*)d_ws;
    unsigned short* xb   = (unsigned short*)(ws);                 // 16MB (reused as attn_out)
    unsigned short* Wb   = (unsigned short*)(ws + (16u << 20));   // 6MB
    unsigned short* Wp   = (unsigned short*)(ws + (22u << 20));   // 2MB
    unsigned short* qbuf = (unsigned short*)(ws + (24u << 20));   // 16MB
    unsigned short* kbuf = (unsigned short*)(ws + (40u << 20));   // 16MB
    float* cosT = (float*)(ws + (56u << 20));                     // 256KB
    float* sinT = (float*)(ws + (56u << 20) + (256u << 10));      // 256KB

    cvt_kernel<<<8388608 / 1024, 256, 0, stream>>>(x, xb, 8388608);
    cvt_kernel<<<3145728 / 1024, 256, 0, stream>>>(qkvw, Wb, 3145728);
    cvt_kernel<<<1048576 / 1024, 256, 0, stream>>>(cpw, Wp, 1048576);
    rope_tables<<<65536 / 256, 256, 0, stream>>>(cosT, sinT);

    gemm_bt<1><<<dim3(64, 24), 256, 0, stream>>>(xb, Wb, 1024,
        qbuf, kbuf, vout, v1, lamb, nullptr, nullptr, cosT, sinT);

    attn_kernel<<<dim3(64, 32), 256, 0, stream>>>(qbuf, kbuf, vout, xb, winp);

    gemm_bt<2><<<dim3(64, 8), 256, 0, stream>>>(xb, Wp, 1024,
        nullptr, nullptr, nullptr, nullptr, nullptr, y, cpb, nullptr, nullptr);
}

// Round 4
// 202.324 us; speedup vs baseline: 1.4987x; 1.0666x over previous
//
#include <hip/hip_runtime.h>
#include <stdint.h>

typedef __attribute__((ext_vector_type(8))) short short8;   // 8 bf16 (4 VGPRs)
typedef __attribute__((ext_vector_type(4))) float f32x4;

#define LDS_AS __attribute__((address_space(3)))
#define GLOB_AS __attribute__((address_space(1)))

__device__ __forceinline__ void gload_lds16(const void* g, void* l) {
    __builtin_amdgcn_global_load_lds((const GLOB_AS uint32_t*)g,
                                     (LDS_AS uint32_t*)l, 16, 0, 0);
}

__device__ __forceinline__ unsigned short f2bf(float f) {
    uint32_t u = __builtin_bit_cast(uint32_t, f);
    u += 0x7fffu + ((u >> 16) & 1u);
    return (unsigned short)(u >> 16);
}
__device__ __forceinline__ float bf2f(unsigned short u) {
    uint32_t v = ((uint32_t)u) << 16;
    return __builtin_bit_cast(float, v);
}

// ---------------- fp32 -> bf16 convert ----------------
__global__ void cvt_kernel(const float* __restrict__ src,
                           unsigned short* __restrict__ dst, int n) {
    int i = (blockIdx.x * blockDim.x + threadIdx.x) * 4;
    if (i < n) {
        float4 v = *(const float4*)(src + i);
        ushort4 o;
        o.x = f2bf(v.x); o.y = f2bf(v.y); o.z = f2bf(v.z); o.w = f2bf(v.w);
        *(ushort4*)(dst + i) = o;
    }
}

// ---------------- rope tables: cos/sin (2048 x 32) ----------------
__global__ void rope_tables(float* __restrict__ cosT, float* __restrict__ sinT) {
    int tid = blockIdx.x * blockDim.x + threadIdx.x;  // 65536
    int t = tid >> 5, i = tid & 31;
    float f = (i < 16) ? exp2f(-10.0f * (float)i / 15.0f) : 0.0f;
    float th = (float)t * f;
    cosT[tid] = cosf(th);
    sinT[tid] = sinf(th);
}

// ---------------- GEMM C[m,n] = sum_k A[m,k]*B[n,k], bf16 in fp32 acc ----
// Double-buffered LDS, prefetch-before-compute, natural dim3 raster (good L2).
// MODE 1: qkv epilogue: q/k get fused RMS-norm + RoPE -> bf16 (B,H,T,64);
//         v -> fp32 d_out (B,H,T,64)  AND  bf16 V^T (B,H,64,T) scratch.
// MODE 2: proj epilogue (fp32 + bias)
template <int MODE>
__global__ __launch_bounds__(256, 3) void gemm_bt(
    const unsigned short* __restrict__ A, const unsigned short* __restrict__ B,
    int K,
    unsigned short* __restrict__ qbuf, unsigned short* __restrict__ kbuf,
    float* __restrict__ vout, unsigned short* __restrict__ vbT,
    const float* __restrict__ v1, const float* __restrict__ lambp,
    float* __restrict__ y, const float* __restrict__ bias,
    const float* __restrict__ cosT, const float* __restrict__ sinT)
{
    __shared__ unsigned short As[2][128 * 32];
    __shared__ unsigned short Bs[2][128 * 32];
    const int tid = threadIdx.x;
    const int lane = tid & 63, w = tid >> 6;
    const int wr = w >> 1, wc = w & 1;
    const int lr = lane & 15, lh = lane >> 4;
    const long m0 = (long)blockIdx.x * 128;
    const long n0 = (long)blockIdx.y * 128;

    const int row0 = w * 16 + (lane >> 2);
    const int colb = (lane & 3) * 16;
    const char* pa0 = (const char*)A + ((m0 + row0) * (long)K) * 2 + colb;
    const char* pa1 = pa0 + 64 * (long)K * 2;
    const char* pb0 = (const char*)B + ((n0 + row0) * (long)K) * 2 + colb;
    const char* pb1 = pb0 + 64 * (long)K * 2;
    char* la = (char*)&As[0][0] + w * 1024;   // wave-uniform LDS dests
    char* lb = (char*)&Bs[0][0] + w * 1024;
    const int BUF = 128 * 32 * 2;             // bytes per LDS buffer

    f32x4 acc[4][4] = {};

    auto STAGE = [&](int bo) {
        gload_lds16(pa0, la + bo);
        gload_lds16(pa1, la + bo + 4096);
        gload_lds16(pb0, lb + bo);
        gload_lds16(pb1, lb + bo + 4096);
        pa0 += 64; pa1 += 64; pb0 += 64; pb1 += 64;
    };
    auto COMPUTE = [&](int bo) {
        const unsigned short* as = (const unsigned short*)((const char*)&As[0][0] + bo);
        const unsigned short* bs = (const unsigned short*)((const char*)&Bs[0][0] + bo);
        short8 a[4], b[4];
        #pragma unroll
        for (int i = 0; i < 4; ++i)
            a[i] = *(const short8*)&as[(wr * 64 + i * 16 + lr) * 32 + lh * 8];
        #pragma unroll
        for (int i = 0; i < 4; ++i)
            b[i] = *(const short8*)&bs[(wc * 64 + i * 16 + lr) * 32 + lh * 8];
        #pragma unroll
        for (int i = 0; i < 4; ++i)
            #pragma unroll
            for (int j = 0; j < 4; ++j)
                acc[i][j] = __builtin_amdgcn_mfma_f32_16x16x32_bf16(
                    a[i], b[j], acc[i][j], 0, 0, 0);
    };

    STAGE(0);
    __syncthreads();
    for (int k0 = 0; k0 < K; k0 += 64) {
        STAGE(BUF);
        COMPUTE(0);
        __syncthreads();
        if (k0 + 64 < K) STAGE(0);
        COMPUTE(BUF);
        __syncthreads();
    }

    if constexpr (MODE == 1) {
        const long nbase = n0 + wc * 64;      // wave-uniform, 64-aligned
        const int kk = (int)(nbase >> 10);    // 0=q 1=k 2=v (uniform)
        const int h = (int)((nbase & 1023) >> 6);
        if (kk == 2) {
            float lam = lambp[0];
            #pragma unroll
            for (int i = 0; i < 4; ++i)
            #pragma unroll
            for (int j = 0; j < 4; ++j)
            #pragma unroll
            for (int r = 0; r < 4; ++r) {
                long m = m0 + wr * 64 + i * 16 + lh * 4 + r;
                int d = j * 16 + lr;
                int rem = h * 64 + d;
                long b_ = m >> 11, t = m & 2047;
                size_t idx = (((size_t)(b_ * 16 + h)) * 2048 + t) * 64 + d;
                float vv = v1[(size_t)m * 1024 + rem];
                float val = (1.0f - lam) * acc[i][j][r] + lam * vv;
                vout[idx] = val;
                vbT[(((size_t)(b_ * 16 + h)) * 64 + d) * 2048 + t] = f2bf(val);
            }
        } else {
            unsigned short* dst = (kk == 0) ? qbuf : kbuf;
            #pragma unroll
            for (int i = 0; i < 4; ++i)
            #pragma unroll
            for (int r = 0; r < 4; ++r) {
                float v0 = acc[i][0][r], v1_ = acc[i][1][r];
                float v2 = acc[i][2][r], v3 = acc[i][3][r];
                float ss = v0 * v0 + v1_ * v1_ + v2 * v2 + v3 * v3;
                ss += __shfl_xor(ss, 1);
                ss += __shfl_xor(ss, 2);
                ss += __shfl_xor(ss, 4);
                ss += __shfl_xor(ss, 8);
                float inv = rsqrtf(ss * (1.0f / 64.0f) + 1e-6f);
                float x0 = v0 * inv, x1 = v1_ * inv;
                float x2 = v2 * inv, x3 = v3 * inv;
                long m = m0 + wr * 64 + i * 16 + lh * 4 + r;
                int t = (int)(m & 2047);
                long b_ = m >> 11;
                float c0 = cosT[t * 32 + lr],      s0 = sinT[t * 32 + lr];
                float c1 = cosT[t * 32 + 16 + lr], s1 = sinT[t * 32 + 16 + lr];
                size_t rb = (((size_t)(b_ * 16 + h)) * 2048 + t) * 64;
                dst[rb + 0 * 16 + lr] = f2bf( x0 * c0 + x2 * s0);
                dst[rb + 1 * 16 + lr] = f2bf( x1 * c1 + x3 * s1);
                dst[rb + 2 * 16 + lr] = f2bf(-x0 * s0 + x2 * c0);
                dst[rb + 3 * 16 + lr] = f2bf(-x1 * s1 + x3 * c1);
            }
        }
    } else {
        #pragma unroll
        for (int i = 0; i < 4; ++i)
        #pragma unroll
        for (int j = 0; j < 4; ++j)
        #pragma unroll
        for (int r = 0; r < 4; ++r) {
            long m = m0 + wr * 64 + i * 16 + lh * 4 + r;
            long n = n0 + wc * 64 + j * 16 + lr;
            y[(size_t)m * 1024 + n] = acc[i][j][r] + bias[n];
        }
    }
}

// ---------------- flash attention, sliding window ----------------
// block = 8 waves (512 thr); block = one (b,h) x 128 q rows; wave = 16 q rows.
// K and V^T tiles double-buffered in LDS via global_load_lds with XOR swizzle:
// LDS(row, slot) holds global chunk (row, slot ^ (row&7)); read applies same XOR.
__global__ __launch_bounds__(512, 2) void attn_kernel(
    const unsigned short* __restrict__ qn, const unsigned short* __restrict__ kn,
    const unsigned short* __restrict__ vtb, unsigned short* __restrict__ attn_out,
    const int* __restrict__ winp)
{
    __shared__ unsigned short Ks[2][64 * 64];    // [key][d], swizzled
    __shared__ unsigned short Vt[2][64 * 64];    // [d][key], swizzled
    __shared__ unsigned short Pl[8][16 * 72];    // per-wave P: [qrow][key]
    const int tid = threadIdx.x, lane = tid & 63, w = tid >> 6;
    const int lr = lane & 15, lh = lane >> 4;
    const int bh = blockIdx.x;                   // 0..63
    const int qt2 = blockIdx.y;                  // 0..15
    const int t0 = qt2 * 128;
    const int win = winp[0];
    const int qrow = t0 + w * 16;

    // Q fragments (registers)
    short8 qf[2];
    #pragma unroll
    for (int ks = 0; ks < 2; ++ks)
        qf[ks] = *(const short8*)&qn[((size_t)bh * 2048 + qrow + lr) * 64 + ks * 32 + lh * 8];

    // staging source addresses (pre-swizzled): thread handles chunk tid
    const int srow = tid >> 3;                         // tile row (key or d)
    const int scol = (tid & 7) ^ (srow & 7);           // swizzled 16B chunk
    const char* kg = (const char*)kn + ((size_t)bh * 2048 + srow) * 128 + scol * 16;
    const char* vg = (const char*)vtb + ((size_t)(bh * 64 + srow)) * 4096 + scol * 16;
    char* lk = (char*)&Ks[0][0] + w * 1024;            // wave-uniform dests
    char* lv = (char*)&Vt[0][0] + w * 1024;

    auto STAGE = [&](int buf, int j0) {
        gload_lds16(kg + (size_t)j0 * 128, lk + buf * 8192);
        gload_lds16(vg + (size_t)j0 * 2,   lv + buf * 8192);
    };

    f32x4 oacc[4] = {};
    float mrow[4], lrow[4];
    #pragma unroll
    for (int r = 0; r < 4; ++r) { mrow[r] = -1e30f; lrow[r] = 0.f; }

    const float C = 0.125f * 1.44269504f;   // scale * log2(e)
    const int kvt0 = max(0, t0 - win + 1) >> 6;
    const int kvt1 = (t0 + 127) >> 6;

    STAGE(0, kvt0 * 64);
    __syncthreads();
    for (int kvt = kvt0; kvt <= kvt1; ++kvt) {
        const int j0 = kvt * 64;
        const int buf = (kvt - kvt0) & 1;
        if (kvt < kvt1) STAGE(buf ^ 1, j0 + 64);

        // wave-uniform skip of fully-masked tiles
        if (j0 <= qrow + 15 && j0 + 63 >= qrow + 16 - win) {
            const char* ksb = (const char*)&Ks[buf][0];
            const char* vtb_ = (const char*)&Vt[buf][0];

            // S = Q K^T  (C[row=q][col=key])
            float sv[4][4];
            #pragma unroll
            for (int kt = 0; kt < 4; ++kt) {
                f32x4 s = {};
                #pragma unroll
                for (int ks = 0; ks < 2; ++ks) {
                    int row = kt * 16 + lr;
                    int off = row * 128 + (((ks * 4 + lh) ^ (row & 7)) * 16);
                    short8 kf = *(const short8*)(ksb + off);
                    s = __builtin_amdgcn_mfma_f32_16x16x32_bf16(qf[ks], kf, s, 0, 0, 0);
                }
                #pragma unroll
                for (int r = 0; r < 4; ++r) {
                    int qi = qrow + lh * 4 + r;
                    int ji = j0 + kt * 16 + lr;
                    bool ok = (ji <= qi) && (qi - ji < win);
                    sv[kt][r] = ok ? s[r] * C : -1e30f;
                }
            }

            // online softmax in exp2 domain (reduce across lr lanes)
            float pn[4][4];
            #pragma unroll
            for (int r = 0; r < 4; ++r) {
                float tm = fmaxf(fmaxf(sv[0][r], sv[1][r]), fmaxf(sv[2][r], sv[3][r]));
                #pragma unroll
                for (int m = 1; m < 16; m <<= 1) tm = fmaxf(tm, __shfl_xor(tm, m));
                float nm = fmaxf(mrow[r], tm);
                float alpha = exp2f(mrow[r] - nm);
                float ps = 0.f;
                #pragma unroll
                for (int kt = 0; kt < 4; ++kt) {
                    float p = exp2f(sv[kt][r] - nm);
                    pn[kt][r] = p; ps += p;
                }
                #pragma unroll
                for (int m = 1; m < 16; m <<= 1) ps += __shfl_xor(ps, m);
                lrow[r] = lrow[r] * alpha + ps;
                mrow[r] = nm;
                #pragma unroll
                for (int dt = 0; dt < 4; ++dt) oacc[dt][r] *= alpha;
            }

            // P -> per-wave LDS (to A-fragment layout)
            #pragma unroll
            for (int kt = 0; kt < 4; ++kt)
                #pragma unroll
                for (int r = 0; r < 4; ++r)
                    Pl[w][(lh * 4 + r) * 72 + kt * 16 + lr] = f2bf(pn[kt][r]);

            short8 pf[2];
            #pragma unroll
            for (int ks = 0; ks < 2; ++ks)
                pf[ks] = *(const short8*)&Pl[w][lr * 72 + ks * 32 + lh * 8];
            #pragma unroll
            for (int dt = 0; dt < 4; ++dt)
                #pragma unroll
                for (int ks = 0; ks < 2; ++ks) {
                    int row = dt * 16 + lr;
                    int off = row * 128 + (((ks * 4 + lh) ^ (row & 7)) * 16);
                    short8 vf = *(const short8*)(vtb_ + off);
                    oacc[dt] = __builtin_amdgcn_mfma_f32_16x16x32_bf16(pf[ks], vf, oacc[dt], 0, 0, 0);
                }
        }
        __syncthreads();   // next stage landed; all waves done with buf
    }

    // write attention output (B,T,C) bf16
    int b = bh >> 4, h = bh & 15;
    #pragma unroll
    for (int dt = 0; dt < 4; ++dt)
        #pragma unroll
        for (int r = 0; r < 4; ++r) {
            int t = qrow + lh * 4 + r;
            float o = oacc[dt][r] / lrow[r];
            attn_out[((size_t)b * 2048 + t) * 1024 + h * 64 + dt * 16 + lr] = f2bf(o);
        }
}

extern "C" void kernel_launch(void* const* d_in, const int* in_sizes, int n_in,
                              void* d_out, int out_size, void* d_ws, size_t ws_size,
                              hipStream_t stream) {
    const float* x    = (const float*)d_in[0];
    const float* v1   = (const float*)d_in[1];
    const float* qkvw = (const float*)d_in[2];
    const float* cpw  = (const float*)d_in[3];
    const float* cpb  = (const float*)d_in[4];
    const float* lamb = (const float*)d_in[5];
    const int*   winp = (const int*)d_in[6];

    float* y    = (float*)d_out;
    float* vout = y + (size_t)8192 * 1024;   // value output (B,H,T,64) fp32

    // V^T bf16 scratch lives in the y region of d_out (16MB of 32MB);
    // proj GEMM fully overwrites y afterwards.
    unsigned short* vbT = (unsigned short*)y;

    char* ws = (char*)d_ws;
    unsigned short* xb   = (unsigned short*)(ws);                 // 16MB (reused as attn_out)
    unsigned short* Wb   = (unsigned short*)(ws + (16u << 20));   // 6MB
    unsigned short* Wp   = (unsigned short*)(ws + (22u << 20));   // 2MB
    unsigned short* qbuf = (unsigned short*)(ws + (24u << 20));   // 16MB
    unsigned short* kbuf = (unsigned short*)(ws + (40u << 20));   // 16MB
    float* cosT = (float*)(ws + (56u << 20));                     // 256KB
    float* sinT = (float*)(ws + (56u << 20) + (256u << 10));      // 256KB

    cvt_kernel<<<8388608 / 1024, 256, 0, stream>>>(x, xb, 8388608);
    cvt_kernel<<<3145728 / 1024, 256, 0, stream>>>(qkvw, Wb, 3145728);
    cvt_kernel<<<1048576 / 1024, 256, 0, stream>>>(cpw, Wp, 1048576);
    rope_tables<<<65536 / 256, 256, 0, stream>>>(cosT, sinT);

    gemm_bt<1><<<dim3(64, 24), 256, 0, stream>>>(xb, Wb, 1024,
        qbuf, kbuf, vout, vbT, v1, lamb, nullptr, nullptr, cosT, sinT);

    attn_kernel<<<dim3(64, 16), 512, 0, stream>>>(qbuf, kbuf, vbT, xb, winp);

    gemm_bt<2><<<dim3(64, 8), 256, 0, stream>>>(xb, Wp, 1024,
        nullptr, nullptr, nullptr, nullptr, nullptr, nullptr, y, cpb, nullptr, nullptr);
}

// Round 5
// 188.181 us; speedup vs baseline: 1.6114x; 1.0752x over previous
//
#include <hip/hip_runtime.h>
#include <stdint.h>

typedef __attribute__((ext_vector_type(8))) short short8;   // 8 bf16 (4 VGPRs)
typedef __attribute__((ext_vector_type(4))) float f32x4;

#define LDS_AS __attribute__((address_space(3)))
#define GLOB_AS __attribute__((address_space(1)))

__device__ __forceinline__ void gload_lds16(const void* g, void* l) {
    __builtin_amdgcn_global_load_lds((const GLOB_AS uint32_t*)g,
                                     (LDS_AS uint32_t*)l, 16, 0, 0);
}

__device__ __forceinline__ unsigned short f2bf(float f) {
    uint32_t u = __builtin_bit_cast(uint32_t, f);
    u += 0x7fffu + ((u >> 16) & 1u);
    return (unsigned short)(u >> 16);
}
__device__ __forceinline__ float bf2f(unsigned short u) {
    uint32_t v = ((uint32_t)u) << 16;
    return __builtin_bit_cast(float, v);
}

// ---------------- fp32 -> bf16 convert ----------------
__global__ void cvt_kernel(const float* __restrict__ src,
                           unsigned short* __restrict__ dst, int n) {
    int i = (blockIdx.x * blockDim.x + threadIdx.x) * 4;
    if (i < n) {
        float4 v = *(const float4*)(src + i);
        ushort4 o;
        o.x = f2bf(v.x); o.y = f2bf(v.y); o.z = f2bf(v.z); o.w = f2bf(v.w);
        *(ushort4*)(dst + i) = o;
    }
}

// ---------------- rope tables: cos/sin (2048 x 32) ----------------
__global__ void rope_tables(float* __restrict__ cosT, float* __restrict__ sinT) {
    int tid = blockIdx.x * blockDim.x + threadIdx.x;  // 65536
    int t = tid >> 5, i = tid & 31;
    float f = (i < 16) ? exp2f(-10.0f * (float)i / 15.0f) : 0.0f;
    float th = (float)t * f;
    cosT[tid] = cosf(th);
    sinT[tid] = sinf(th);
}

// ---- GEMM C[m,n] = sum_k A[m,k]*B[n,k], bf16, fp32 acc -----------------
// Phase-pipelined: BM=256 BN=128 BK=64, 8 waves (4M x 2N, 64x64 per wave),
// 3-K-tile LDS ring (A 3x32KB + B 3x16KB = 144KB), prefetch 2 tiles ahead,
// counted vmcnt(6) (never 0 until tail). LDS chunk-XOR swizzle (c ^= row&7)
// applied on BOTH sides: pre-swizzled global source + swizzled ds_read.
// MODE 1: qkv epilogue (q/k: fused RMS+RoPE -> bf16 (B,H,T,64); v: lerp ->
//         fp32 d_out AND bf16 V^T scratch).  MODE 2: proj epilogue (+bias).
template <int MODE>
__global__ __launch_bounds__(512, 2) void gemm8p(
    const unsigned short* __restrict__ A, const unsigned short* __restrict__ B,
    int K,
    unsigned short* __restrict__ qbuf, unsigned short* __restrict__ kbuf,
    float* __restrict__ vout, unsigned short* __restrict__ vbT,
    const float* __restrict__ v1, const float* __restrict__ lambp,
    float* __restrict__ y, const float* __restrict__ bias,
    const float* __restrict__ cosT, const float* __restrict__ sinT)
{
    __shared__ __align__(16) char smem[147456];   // A ring 98304 + B ring 49152
    char* const AL = smem;
    char* const BL = smem + 98304;
    const int tid = threadIdx.x, lane = tid & 63, w = tid >> 6;
    const int wr = w >> 1, wc = w & 1;            // 4M x 2N waves
    const int lr = lane & 15, lh = lane >> 4;
    const long m0 = (long)blockIdx.x * 256;
    const long n0 = (long)blockIdx.y * 128;
    const int NT = K >> 6;                        // 16

    // ---- staging addresses: thread t handles chunk (l*512 + t) per tile ----
    const int srow = tid >> 3;                    // 0..63
    const int swc  = (tid & 7) ^ (srow & 7);      // pre-swizzled source chunk
    const long rsb = (long)K * 2;
    const char* pa0 = (const char*)A + (m0 + srow +   0) * rsb + swc * 16;
    const char* pa1 = (const char*)A + (m0 + srow +  64) * rsb + swc * 16;
    const char* pa2 = (const char*)A + (m0 + srow + 128) * rsb + swc * 16;
    const char* pa3 = (const char*)A + (m0 + srow + 192) * rsb + swc * 16;
    const char* pb0 = (const char*)B + (n0 + srow +   0) * rsb + swc * 16;
    const char* pb1 = (const char*)B + (n0 + srow +  64) * rsb + swc * 16;
    char* const lA = AL + w * 1024;               // wave-uniform LDS dests
    char* const lB = BL + w * 1024;

    auto STAGE_A3 = [&](int aoff, int boff) {     // first 3 of 6 loads
        gload_lds16(pa0, lA + aoff);
        gload_lds16(pa1, lA + aoff + 8192);
        gload_lds16(pb0, lB + boff);
    };
    auto STAGE_B3 = [&](int aoff, int boff) {     // last 3, then bump k
        gload_lds16(pa2, lA + aoff + 16384);
        gload_lds16(pa3, lA + aoff + 24576);
        gload_lds16(pb1, lB + boff + 8192);
        pa0 += 128; pa1 += 128; pa2 += 128; pa3 += 128;
        pb0 += 128; pb1 += 128;
    };

    // ---- fragment-read invariants (swizzled) ----
    const int arow_b = (wr * 64 + lr) * 128;      // A row byte base
    const int brow_b = (wc * 64 + lr) * 128;      // B row byte base
    const int x0 = ((lh)     ^ (lr & 7)) * 16;    // ks=0 chunk byte
    const int x1 = ((4 + lh) ^ (lr & 7)) * 16;    // ks=1 chunk byte

    f32x4 acc[4][4] = {};

    // ---- prologue: stage T0 -> slot0, T1 -> slot1 ----
    STAGE_A3(0, 0);           STAGE_B3(0, 0);
    STAGE_A3(32768, 16384);   STAGE_B3(32768, 16384);

    int cA = 0, cB = 0;                 // compute-slot offsets
    int sA = 65536, sB = 32768;         // stage-slot offsets (t+2)

    for (int t = 0; t < NT; ++t) {
        // T_t resident: all but the newest 6 loads (T_{t+1}) must be done
        if (t < NT - 1) asm volatile("s_waitcnt vmcnt(6)" ::: "memory");
        else            asm volatile("s_waitcnt vmcnt(0)" ::: "memory");
        __builtin_amdgcn_s_barrier();
        __builtin_amdgcn_sched_barrier(0);

        const char* ab = AL + cA;
        const char* bb = BL + cB;
        const bool st = (t < NT - 2);

        // ---- phase A: B frags (whole tile) + A frags mi=0,1 ----
        short8 bfr[4][2], afr[2][2];
        #pragma unroll
        for (int ni = 0; ni < 4; ++ni) {
            bfr[ni][0] = *(const short8*)(bb + brow_b + ni * 2048 + x0);
            bfr[ni][1] = *(const short8*)(bb + brow_b + ni * 2048 + x1);
        }
        #pragma unroll
        for (int mi = 0; mi < 2; ++mi) {
            afr[mi][0] = *(const short8*)(ab + arow_b + mi * 2048 + x0);
            afr[mi][1] = *(const short8*)(ab + arow_b + mi * 2048 + x1);
        }
        if (st) STAGE_A3(sA, sB);
        __builtin_amdgcn_s_barrier();
        asm volatile("s_waitcnt lgkmcnt(0)" ::: "memory");
        __builtin_amdgcn_sched_barrier(0);
        __builtin_amdgcn_s_setprio(1);
        #pragma unroll
        for (int mi = 0; mi < 2; ++mi)
            #pragma unroll
            for (int ni = 0; ni < 4; ++ni)
                #pragma unroll
                for (int ks = 0; ks < 2; ++ks)
                    acc[mi][ni] = __builtin_amdgcn_mfma_f32_16x16x32_bf16(
                        afr[mi][ks], bfr[ni][ks], acc[mi][ni], 0, 0, 0);
        __builtin_amdgcn_s_setprio(0);
        __builtin_amdgcn_s_barrier();

        // ---- phase B: A frags mi=2,3 ----
        short8 afr2[2][2];
        #pragma unroll
        for (int mi = 0; mi < 2; ++mi) {
            afr2[mi][0] = *(const short8*)(ab + arow_b + (mi + 2) * 2048 + x0);
            afr2[mi][1] = *(const short8*)(ab + arow_b + (mi + 2) * 2048 + x1);
        }
        if (st) STAGE_B3(sA, sB);
        __builtin_amdgcn_s_barrier();
        asm volatile("s_waitcnt lgkmcnt(0)" ::: "memory");
        __builtin_amdgcn_sched_barrier(0);
        __builtin_amdgcn_s_setprio(1);
        #pragma unroll
        for (int mi = 0; mi < 2; ++mi)
            #pragma unroll
            for (int ni = 0; ni < 4; ++ni)
                #pragma unroll
                for (int ks = 0; ks < 2; ++ks)
                    acc[mi + 2][ni] = __builtin_amdgcn_mfma_f32_16x16x32_bf16(
                        afr2[mi][ks], bfr[ni][ks], acc[mi + 2][ni], 0, 0, 0);
        __builtin_amdgcn_s_setprio(0);
        // (next iter's leading barrier separates)

        cA = (cA == 65536) ? 0 : cA + 32768;
        cB = (cB == 32768) ? 0 : cB + 16384;
        sA = (sA == 65536) ? 0 : sA + 32768;
        sB = (sB == 32768) ? 0 : sB + 16384;
    }

    // ---- epilogues (per-wave 64x64 at rows m0+wr*64, cols n0+wc*64) ----
    if constexpr (MODE == 1) {
        const long nbase = n0 + wc * 64;      // wave-uniform, 64-aligned
        const int kk = (int)(nbase >> 10);    // 0=q 1=k 2=v (uniform)
        const int h = (int)((nbase & 1023) >> 6);
        if (kk == 2) {
            float lam = lambp[0];
            #pragma unroll
            for (int i = 0; i < 4; ++i)
            #pragma unroll
            for (int j = 0; j < 4; ++j)
            #pragma unroll
            for (int r = 0; r < 4; ++r) {
                long m = m0 + wr * 64 + i * 16 + lh * 4 + r;
                int d = j * 16 + lr;
                int rem = h * 64 + d;
                long b_ = m >> 11, t = m & 2047;
                size_t idx = (((size_t)(b_ * 16 + h)) * 2048 + t) * 64 + d;
                float vv = v1[(size_t)m * 1024 + rem];
                float val = (1.0f - lam) * acc[i][j][r] + lam * vv;
                vout[idx] = val;
                vbT[(((size_t)(b_ * 16 + h)) * 64 + d) * 2048 + t] = f2bf(val);
            }
        } else {
            unsigned short* dst = (kk == 0) ? qbuf : kbuf;
            #pragma unroll
            for (int i = 0; i < 4; ++i)
            #pragma unroll
            for (int r = 0; r < 4; ++r) {
                float v0 = acc[i][0][r], v1_ = acc[i][1][r];
                float v2 = acc[i][2][r], v3 = acc[i][3][r];
                float ss = v0 * v0 + v1_ * v1_ + v2 * v2 + v3 * v3;
                ss += __shfl_xor(ss, 1);
                ss += __shfl_xor(ss, 2);
                ss += __shfl_xor(ss, 4);
                ss += __shfl_xor(ss, 8);
                float inv = rsqrtf(ss * (1.0f / 64.0f) + 1e-6f);
                float x0f = v0 * inv, x1f = v1_ * inv;
                float x2f = v2 * inv, x3f = v3 * inv;
                long m = m0 + wr * 64 + i * 16 + lh * 4 + r;
                int t = (int)(m & 2047);
                long b_ = m >> 11;
                float c0 = cosT[t * 32 + lr],      s0 = sinT[t * 32 + lr];
                float c1 = cosT[t * 32 + 16 + lr], s1 = sinT[t * 32 + 16 + lr];
                size_t rb = (((size_t)(b_ * 16 + h)) * 2048 + t) * 64;
                dst[rb + 0 * 16 + lr] = f2bf( x0f * c0 + x2f * s0);
                dst[rb + 1 * 16 + lr] = f2bf( x1f * c1 + x3f * s1);
                dst[rb + 2 * 16 + lr] = f2bf(-x0f * s0 + x2f * c0);
                dst[rb + 3 * 16 + lr] = f2bf(-x1f * s1 + x3f * c1);
            }
        }
    } else {
        #pragma unroll
        for (int i = 0; i < 4; ++i)
        #pragma unroll
        for (int j = 0; j < 4; ++j)
        #pragma unroll
        for (int r = 0; r < 4; ++r) {
            long m = m0 + wr * 64 + i * 16 + lh * 4 + r;
            long n = n0 + wc * 64 + j * 16 + lr;
            y[(size_t)m * 1024 + n] = acc[i][j][r] + bias[n];
        }
    }
}

// ---------------- flash attention, sliding window ----------------
// block = 8 waves (512 thr); block = one (b,h) x 128 q rows; wave = 16 q rows.
// K and V^T tiles double-buffered in LDS via global_load_lds with XOR swizzle:
// LDS(row, slot) holds global chunk (row, slot ^ (row&7)); read applies same XOR.
__global__ __launch_bounds__(512, 2) void attn_kernel(
    const unsigned short* __restrict__ qn, const unsigned short* __restrict__ kn,
    const unsigned short* __restrict__ vtb, unsigned short* __restrict__ attn_out,
    const int* __restrict__ winp)
{
    __shared__ unsigned short Ks[2][64 * 64];    // [key][d], swizzled
    __shared__ unsigned short Vt[2][64 * 64];    // [d][key], swizzled
    __shared__ unsigned short Pl[8][16 * 72];    // per-wave P: [qrow][key]
    const int tid = threadIdx.x, lane = tid & 63, w = tid >> 6;
    const int lr = lane & 15, lh = lane >> 4;
    const int bh = blockIdx.x;                   // 0..63
    const int qt2 = blockIdx.y;                  // 0..15
    const int t0 = qt2 * 128;
    const int win = winp[0];
    const int qrow = t0 + w * 16;

    short8 qf[2];
    #pragma unroll
    for (int ks = 0; ks < 2; ++ks)
        qf[ks] = *(const short8*)&qn[((size_t)bh * 2048 + qrow + lr) * 64 + ks * 32 + lh * 8];

    const int srow = tid >> 3;
    const int scol = (tid & 7) ^ (srow & 7);
    const char* kg = (const char*)kn + ((size_t)bh * 2048 + srow) * 128 + scol * 16;
    const char* vg = (const char*)vtb + ((size_t)(bh * 64 + srow)) * 4096 + scol * 16;
    char* lk = (char*)&Ks[0][0] + w * 1024;
    char* lv = (char*)&Vt[0][0] + w * 1024;

    auto STAGE = [&](int buf, int j0) {
        gload_lds16(kg + (size_t)j0 * 128, lk + buf * 8192);
        gload_lds16(vg + (size_t)j0 * 2,   lv + buf * 8192);
    };

    f32x4 oacc[4] = {};
    float mrow[4], lrow[4];
    #pragma unroll
    for (int r = 0; r < 4; ++r) { mrow[r] = -1e30f; lrow[r] = 0.f; }

    const float C = 0.125f * 1.44269504f;   // scale * log2(e)
    const int kvt0 = max(0, t0 - win + 1) >> 6;
    const int kvt1 = (t0 + 127) >> 6;

    STAGE(0, kvt0 * 64);
    __syncthreads();
    for (int kvt = kvt0; kvt <= kvt1; ++kvt) {
        const int j0 = kvt * 64;
        const int buf = (kvt - kvt0) & 1;
        if (kvt < kvt1) STAGE(buf ^ 1, j0 + 64);

        if (j0 <= qrow + 15 && j0 + 63 >= qrow + 16 - win) {
            const char* ksb = (const char*)&Ks[buf][0];
            const char* vtb_ = (const char*)&Vt[buf][0];

            float sv[4][4];
            #pragma unroll
            for (int kt = 0; kt < 4; ++kt) {
                f32x4 s = {};
                #pragma unroll
                for (int ks = 0; ks < 2; ++ks) {
                    int row = kt * 16 + lr;
                    int off = row * 128 + (((ks * 4 + lh) ^ (row & 7)) * 16);
                    short8 kf = *(const short8*)(ksb + off);
                    s = __builtin_amdgcn_mfma_f32_16x16x32_bf16(qf[ks], kf, s, 0, 0, 0);
                }
                #pragma unroll
                for (int r = 0; r < 4; ++r) {
                    int qi = qrow + lh * 4 + r;
                    int ji = j0 + kt * 16 + lr;
                    bool ok = (ji <= qi) && (qi - ji < win);
                    sv[kt][r] = ok ? s[r] * C : -1e30f;
                }
            }

            float pn[4][4];
            #pragma unroll
            for (int r = 0; r < 4; ++r) {
                float tm = fmaxf(fmaxf(sv[0][r], sv[1][r]), fmaxf(sv[2][r], sv[3][r]));
                #pragma unroll
                for (int m = 1; m < 16; m <<= 1) tm = fmaxf(tm, __shfl_xor(tm, m));
                float nm = fmaxf(mrow[r], tm);
                float alpha = exp2f(mrow[r] - nm);
                float ps = 0.f;
                #pragma unroll
                for (int kt = 0; kt < 4; ++kt) {
                    float p = exp2f(sv[kt][r] - nm);
                    pn[kt][r] = p; ps += p;
                }
                #pragma unroll
                for (int m = 1; m < 16; m <<= 1) ps += __shfl_xor(ps, m);
                lrow[r] = lrow[r] * alpha + ps;
                mrow[r] = nm;
                #pragma unroll
                for (int dt = 0; dt < 4; ++dt) oacc[dt][r] *= alpha;
            }

            #pragma unroll
            for (int kt = 0; kt < 4; ++kt)
                #pragma unroll
                for (int r = 0; r < 4; ++r)
                    Pl[w][(lh * 4 + r) * 72 + kt * 16 + lr] = f2bf(pn[kt][r]);

            short8 pf[2];
            #pragma unroll
            for (int ks = 0; ks < 2; ++ks)
                pf[ks] = *(const short8*)&Pl[w][lr * 72 + ks * 32 + lh * 8];
            #pragma unroll
            for (int dt = 0; dt < 4; ++dt)
                #pragma unroll
                for (int ks = 0; ks < 2; ++ks) {
                    int row = dt * 16 + lr;
                    int off = row * 128 + (((ks * 4 + lh) ^ (row & 7)) * 16);
                    short8 vf = *(const short8*)(vtb_ + off);
                    oacc[dt] = __builtin_amdgcn_mfma_f32_16x16x32_bf16(pf[ks], vf, oacc[dt], 0, 0, 0);
                }
        }
        __syncthreads();
    }

    int b = bh >> 4, h = bh & 15;
    #pragma unroll
    for (int dt = 0; dt < 4; ++dt)
        #pragma unroll
        for (int r = 0; r < 4; ++r) {
            int t = qrow + lh * 4 + r;
            float o = oacc[dt][r] / lrow[r];
            attn_out[((size_t)b * 2048 + t) * 1024 + h * 64 + dt * 16 + lr] = f2bf(o);
        }
}

extern "C" void kernel_launch(void* const* d_in, const int* in_sizes, int n_in,
                              void* d_out, int out_size, void* d_ws, size_t ws_size,
                              hipStream_t stream) {
    const float* x    = (const float*)d_in[0];
    const float* v1   = (const float*)d_in[1];
    const float* qkvw = (const float*)d_in[2];
    const float* cpw  = (const float*)d_in[3];
    const float* cpb  = (const float*)d_in[4];
    const float* lamb = (const float*)d_in[5];
    const int*   winp = (const int*)d_in[6];

    float* y    = (float*)d_out;
    float* vout = y + (size_t)8192 * 1024;   // value output (B,H,T,64) fp32

    // V^T bf16 scratch lives in the y region of d_out; proj overwrites y after.
    unsigned short* vbT = (unsigned short*)y;

    char* ws = (char*)d_ws;
    unsigned short* xb   = (unsigned short*)(ws);                 // 16MB (reused as attn_out)
    unsigned short* Wb   = (unsigned short*)(ws + (16u << 20));   // 6MB
    unsigned short* Wp   = (unsigned short*)(ws + (22u << 20));   // 2MB
    unsigned short* qbuf = (unsigned short*)(ws + (24u << 20));   // 16MB
    unsigned short* kbuf = (unsigned short*)(ws + (40u << 20));   // 16MB
    float* cosT = (float*)(ws + (56u << 20));                     // 256KB
    float* sinT = (float*)(ws + (56u << 20) + (256u << 10));      // 256KB

    cvt_kernel<<<8388608 / 1024, 256, 0, stream>>>(x, xb, 8388608);
    cvt_kernel<<<3145728 / 1024, 256, 0, stream>>>(qkvw, Wb, 3145728);
    cvt_kernel<<<1048576 / 1024, 256, 0, stream>>>(cpw, Wp, 1048576);
    rope_tables<<<65536 / 256, 256, 0, stream>>>(cosT, sinT);

    gemm8p<1><<<dim3(32, 24), 512, 0, stream>>>(xb, Wb, 1024,
        qbuf, kbuf, vout, vbT, v1, lamb, nullptr, nullptr, cosT, sinT);

    attn_kernel<<<dim3(64, 16), 512, 0, stream>>>(qbuf, kbuf, vbT, xb, winp);

    gemm8p<2><<<dim3(32, 8), 512, 0, stream>>>(xb, Wp, 1024,
        nullptr, nullptr, nullptr, nullptr, nullptr, nullptr, y, cpb, nullptr, nullptr);
}